// Round 10
// baseline (160.903 us; speedup 1.0000x reference)
//
#include <hip/hip_runtime.h>
#include <math.h>

#define B_N 2048
#define DIM 32
#define K_N 10
#define NP  528          // sorted pairs (i<=j)
#define NCOLP 640        // padded column count (5 tiles x 128)
#define TILE 128
#define NT 5
#define NBLK (NT*NT*K_N)   // 250 blocks = full grid
#define NR 2368            // padded sample rows: 2048 + 10*32
#define NPAD (NR - B_N)    // 320
#define NRC (NR / 8)       // 296 sample-chunks

typedef __attribute__((ext_vector_type(8))) short bf16x8;   // 8 bf16 = 4 VGPRs
typedef __attribute__((ext_vector_type(4))) float f32x4;    // mfma 16x16 accum

// ---- ws layout (4-byte words); memset zeroes words 0..63 every launch ----
#define WS_CW     0               // cw[10]
#define WS_OFFP   16              // offp[11]
#define WS_CURSOR 32              // cursor[10]
#define WS_LOSS   48
#define WS_CTR    49
#define WS_BAR    50              // bar[4]
#define WS_KB     64              // kb[2048]
#define WS_DIFFC  2112            // NR*32 floats = 75776 words
#define WS_VT     (2112 + 75776)  // ushort[NRC][NCOLP][8]

__device__ __forceinline__ float c2f(float x) {
  float r = sqrtf(fabsf(x) + 0.25f) - 0.5f;
  return (x >= 0.f) ? r : -r;
}
__device__ __forceinline__ float c3f(float x) {
  float v = fabsf(x) + 0.19245008973f;
  float r = exp2f(log2f(v) * 0.33333333333f) - 0.57735026919f;
  return (x >= 0.f) ? r : -r;
}
__device__ __forceinline__ float c4f(float x) {
  float r = sqrtf(sqrtf(fabsf(x) + 0.15749013123f)) - 0.62996052494f;
  return (x >= 0.f) ? r : -r;
}
#define T4C1 (sqrtf(sqrtf(1.f + 0.15749013123f)) - 0.62996052494f)

// col -> (u,v) with d[32]=1 (ones), d[33]=0 (pad)
__device__ __forceinline__ void decode_col(int g, int& u, int& v) {
  if (g < NP) {
    int j = (int)((sqrtf(8.f * (float)g + 1.f) - 1.f) * 0.5f);
    while (j * (j + 1) / 2 > g) --j;
    while ((j + 1) * (j + 2) / 2 <= g) ++j;
    u = g - j * (j + 1) / 2; v = j;
  } else if (g < 560) { u = g - NP; v = 32; }
  else if (g == 560)  { u = 32; v = 32; }
  else                { u = 33; v = 33; }
}

// fp32 -> bf16 bits, round-to-nearest-even
__device__ __forceinline__ unsigned short f2bf(float f) {
  unsigned u = __builtin_bit_cast(unsigned, f);
  return (unsigned short)((u + 0x7FFFu + ((u >> 16) & 1u)) >> 16);
}

// grid-wide barrier: device-scope release add + acquire spin (all blocks resident)
__device__ __forceinline__ void gridbar(int* bar) {
  __syncthreads();
  if (threadIdx.x == 0) {
    __threadfence();                                   // release: flush writes device-wide
    __hip_atomic_fetch_add(bar, 1, __ATOMIC_RELEASE, __HIP_MEMORY_SCOPE_AGENT);
    while (__hip_atomic_load(bar, __ATOMIC_ACQUIRE, __HIP_MEMORY_SCOPE_AGENT) < NBLK)
      __builtin_amdgcn_s_sleep(2);
    __threadfence();                                   // acquire: invalidate stale lines
  }
  __syncthreads();
}

// ---- the single fused kernel (250 blocks x 256 threads, all co-resident) ----
__global__ __launch_bounds__(256) void k_fused(const float* __restrict__ emb,
                                               const float* __restrict__ cen,
                                               const float* __restrict__ lg,
                                               int* __restrict__ wsi,
                                               float* __restrict__ wsf,
                                               float* __restrict__ out) {
  int*   cw     = wsi + WS_CW;
  int*   offp   = wsi + WS_OFFP;
  int*   cursor = wsi + WS_CURSOR;
  float* lossAcc= wsf + WS_LOSS;
  int*   ctr    = wsi + WS_CTR;
  int*   bar    = wsi + WS_BAR;
  int*   kb     = wsi + WS_KB;
  float* diffc  = wsf + WS_DIFFC;
  unsigned short* Vt = (unsigned short*)(wsf + WS_VT);

  const int bid = blockIdx.x;
  const int t   = threadIdx.x;

  // ---- phase 1: argmax + ballot histogram (blocks 0..7) ----
  if (bid < 8) {
    int b = bid * 256 + t;
    const float* l = lg + (size_t)b * K_N;
    float best = l[0]; int bi = 0;
    #pragma unroll
    for (int k = 1; k < K_N; ++k) { float v = l[k]; if (v > best) { best = v; bi = k; } }
    kb[b] = bi;
    #pragma unroll
    for (int k = 0; k < K_N; ++k) {
      unsigned long long m = __ballot(bi == k);
      if ((t & 63) == 0 && m) atomicAdd(&cw[k], (int)__popcll(m));
    }
  }
  gridbar(&bar[0]);

  // ---- phase 2: padded exclusive scan (block 0) ----
  if (bid == 0 && t == 0) {
    int s = 0;
    #pragma unroll
    for (int k = 0; k < K_N; ++k) { offp[k] = s; s += (cw[k] + 31) & ~31; }
    offp[K_N] = s;
  }
  gridbar(&bar[1]);

  // ---- phase 3: compact scatter + pad-zero (blocks 0..9) ----
  if (bid < 10) {
    int idx = bid * 256 + t;
    if (idx < B_N) {
      int k = kb[idx];
      int pos = offp[k] + atomicAdd(&cursor[k], 1);
      const float4* e4 = reinterpret_cast<const float4*>(emb + (size_t)idx * DIM);
      const float4* c4p = reinterpret_cast<const float4*>(cen + (size_t)k * DIM);
      float4* o4 = reinterpret_cast<float4*>(diffc + (size_t)pos * DIM);
      #pragma unroll
      for (int q = 0; q < 8; ++q) {
        float4 e = e4[q], c = c4p[q];
        o4[q] = make_float4(e.x - c.x, e.y - c.y, e.z - c.z, e.w - c.w);
      }
    } else if (idx < NR) {
      int p = idx - B_N;
      int cp = 0, row = -1;
      #pragma unroll
      for (int kk = 0; kk < K_N; ++kk) {
        int nb = cw[kk];
        int pad = ((nb + 31) & ~31) - nb;
        if (row < 0 && p < cp + pad) row = offp[kk] + nb + (p - cp);
        cp += pad;
      }
      if (row < 0) row = offp[K_N] + (p - cp);
      if (row < NR) {
        float4* o4 = reinterpret_cast<float4*>(diffc + (size_t)row * DIM);
        #pragma unroll
        for (int q = 0; q < 8; ++q) o4[q] = make_float4(0.f, 0.f, 0.f, 0.f);
      }
    }
  }
  gridbar(&bar[2]);

  // ---- phase 4: expand diffc -> Vt[chunk][col][8] bf16 (chunks over all blocks) ----
  {
    __shared__ float sd[8][36];
    for (int c = bid; c < NRC; c += NBLK) {
      if (t < 64) {
        int row = t >> 3, d4 = t & 7;
        float4 v = *reinterpret_cast<const float4*>(&diffc[(size_t)(c * 8 + row) * DIM + d4 * 4]);
        *reinterpret_cast<float4*>(&sd[row][d4 * 4]) = v;
        if (d4 == 0) { sd[row][32] = 1.f; sd[row][33] = 0.f; }
      }
      __syncthreads();
      for (int cc = t; cc < NCOLP; cc += 256) {
        int u, v; decode_col(cc, u, v);
        bf16x8 pack;
        #pragma unroll
        for (int e = 0; e < 8; ++e)
          pack[e] = (short)f2bf(sd[e][u] * sd[e][v]);
        *reinterpret_cast<bf16x8*>(Vt + ((size_t)c * NCOLP + cc) * 8) = pack;
      }
      __syncthreads();
    }
  }
  gridbar(&bar[3]);

  // ---- phase 5: MFMA Gram + fused loss (algebra validated r2/r5/r6/r8, absmax 0) ----
  const int k  = bid / 25;
  const int rem = bid % 25;
  const int Pt = rem / 5, Qt = rem % 5;
  const int nb = cw[k];
  const int base = offp[k];              // multiple of 32
  const int nbp = (nb + 31) & ~31;
  const int w = t >> 6, l = t & 63;
  const int wr = w >> 1, wc = w & 1;
  const int lr = l & 15, kg = l >> 4;

  __shared__ unsigned char tI0[NCOLP], tI1[NCOLP];
  __shared__ float sred[4];
  for (int c = t; c < NCOLP; c += 256) {
    int u, v; decode_col(c, u, v);
    tI0[c] = (unsigned char)u; tI1[c] = (unsigned char)v;
  }

  const int pb = Pt * TILE + wr * 64;
  const int qb = Qt * TILE + wc * 64;

  f32x4 acc[4][4];
  {
    f32x4 z = {0.f, 0.f, 0.f, 0.f};
    #pragma unroll
    for (int a = 0; a < 4; ++a)
      #pragma unroll
      for (int c = 0; c < 4; ++c) acc[a][c] = z;
  }

  if (nbp > 0) {
    const int cbase = base >> 3;
    const unsigned short* Ap = Vt + ((size_t)(cbase + kg) * NCOLP + pb + lr) * 8;
    const unsigned short* Bp = Vt + ((size_t)(cbase + kg) * NCOLP + qb + lr) * 8;
    bf16x8 a[4], b[4];
    #pragma unroll
    for (int f = 0; f < 4; ++f) {
      a[f] = *reinterpret_cast<const bf16x8*>(Ap + (size_t)(f * 16) * 8);
      b[f] = *reinterpret_cast<const bf16x8*>(Bp + (size_t)(f * 16) * 8);
    }
    for (int k0 = 32; k0 <= nbp; k0 += 32) {
      bf16x8 an[4], bn[4];
      const bool more = (k0 < nbp);
      if (more) {
        #pragma unroll
        for (int f = 0; f < 4; ++f) {
          an[f] = *reinterpret_cast<const bf16x8*>(Ap + (size_t)k0 * NCOLP + (size_t)(f * 16) * 8);
          bn[f] = *reinterpret_cast<const bf16x8*>(Bp + (size_t)k0 * NCOLP + (size_t)(f * 16) * 8);
        }
      }
      #pragma unroll
      for (int fa = 0; fa < 4; ++fa)
        #pragma unroll
        for (int fc = 0; fc < 4; ++fc)
          acc[fa][fc] = __builtin_amdgcn_mfma_f32_16x16x32_bf16(a[fa], b[fc], acc[fa][fc], 0, 0, 0);
      if (more) {
        #pragma unroll
        for (int f = 0; f < 4; ++f) { a[f] = an[f]; b[f] = bn[f]; }
      }
    }
  }
  __syncthreads();

  // C/D layout (m89-verified): Q(col) = lane&15, P(row) = (lane>>4)*4 + reg
  const float inv_cnt = 1.f / ((float)nb + 1e-7f);
  float sum = 0.f;
  #pragma unroll
  for (int fa = 0; fa < 4; ++fa) {
    #pragma unroll
    for (int r = 0; r < 4; ++r) {
      const int P = pb + fa * 16 + kg * 4 + r;
      const int i = tI0[P], j = tI1[P];
      #pragma unroll
      for (int fc = 0; fc < 4; ++fc) {
        const int Q = qb + fc * 16 + lr;
        const int li = tI0[Q], mi = tI1[Q];
        const float g = acc[fa][fc][r];
        if (P < NP) {
          if (Q < NP) {
            int s0 = min(i, li), x1 = max(i, li), x2 = min(j, mi), s3 = max(j, mi);
            int s1 = min(x1, x2), s2 = max(x1, x2);
            bool e01 = (s0 == s1), e12 = (s1 == s2), e23 = (s2 == s3);
            float wgt, tgt = 0.f;
            if (e01 && e12 && e23)                 wgt = 0.f;
            else if (e01 && e23)                   { wgt = 2.f / 9.f; tgt = T4C1; }
            else if ((e01 && e12) || (e12 && e23)) wgt = 0.25f;
            else if (e01 || e12 || e23)            wgt = 5.f / 24.f;
            else                                   wgt = 1.f / 6.f;
            float d = c4f(g) - tgt;
            sum += 0.125f * wgt * d * d;
          } else if (Q < 560) {
            if (Q - NP >= j) { float d = c3f(g); sum += 0.25f * d * d; }
          } else if (Q == 560) {
            if (i < j) { float d = c2f(g * inv_cnt); sum += 0.5f * d * d; }
          }
        } else if (P < 560 && Q == 560) {
          float m1 = g * inv_cnt;
          sum += m1 * m1;
        }
      }
    }
  }

  #pragma unroll
  for (int off = 32; off > 0; off >>= 1) sum += __shfl_down(sum, off, 64);
  if ((t & 63) == 0) sred[t >> 6] = sum;
  __syncthreads();
  if (t == 0) {
    float s = sred[0] + sred[1] + sred[2] + sred[3];
    atomicAdd(lossAcc, s * ((float)nb * (1.f / (float)B_N)));
    __threadfence();
    if (atomicAdd(ctr, 1) == NBLK - 1) out[0] = atomicAdd(lossAcc, 0.f);
  }
}

extern "C" void kernel_launch(void* const* d_in, const int* in_sizes, int n_in,
                              void* d_out, int out_size, void* d_ws, size_t ws_size,
                              hipStream_t stream) {
  const float* emb = (const float*)d_in[0];
  const float* cen = (const float*)d_in[1];
  const float* lg  = (const float*)d_in[2];
  float* out = (float*)d_out;
  int*   wsi = (int*)d_ws;
  float* wsf = (float*)d_ws;

  (void)hipMemsetAsync(d_ws, 0, 64 * 4, stream);   // cw/offp/cursor/loss/ctr/bars
  k_fused<<<NBLK, 256, 0, stream>>>(emb, cen, lg, wsi, wsf, out);
}

// Round 11
// 44.947 us; speedup vs baseline: 3.5798x; 3.5798x over previous
//
#include <hip/hip_runtime.h>
#include <math.h>

#define B_N 2048
#define DIM 32
#define K_N 10
#define NP  528          // sorted pairs (i<=j)
#define NCOLP 640        // padded column count (5 tiles x 128)
#define TILE 128
#define NT 5
#define NBLK (NT*NT*K_N)   // 250 blocks

typedef __attribute__((ext_vector_type(8))) short bf16x8;   // 8 bf16 = 4 VGPRs
typedef __attribute__((ext_vector_type(4))) float f32x4;    // mfma 16x16 accum

// ---- ws layout (4-byte words); memset zeroes words 0..63 each launch ----
#define WS_LOSS 0
#define WS_CTR  1
#define WS_CWP  16        // cwp[8][16] partial counts (plain stores, no zero needed)
#define WS_KB   160       // kb[2048] int

__device__ __forceinline__ float c2f(float x) {
  float r = sqrtf(fabsf(x) + 0.25f) - 0.5f;
  return (x >= 0.f) ? r : -r;
}
__device__ __forceinline__ float c3f(float x) {
  float v = fabsf(x) + 0.19245008973f;
  float r = exp2f(log2f(v) * 0.33333333333f) - 0.57735026919f;
  return (x >= 0.f) ? r : -r;
}
__device__ __forceinline__ float c4f(float x) {
  float r = sqrtf(sqrtf(fabsf(x) + 0.15749013123f)) - 0.62996052494f;
  return (x >= 0.f) ? r : -r;
}
#define T4C1 (sqrtf(sqrtf(1.f + 0.15749013123f)) - 0.62996052494f)

// col -> (u,v) with d[32]=1 (ones), d[33]=0 (pad)
__device__ __forceinline__ void decode_col(int g, int& u, int& v) {
  if (g < NP) {
    int j = (int)((sqrtf(8.f * (float)g + 1.f) - 1.f) * 0.5f);
    while (j * (j + 1) / 2 > g) --j;
    while ((j + 1) * (j + 2) / 2 <= g) ++j;
    u = g - j * (j + 1) / 2; v = j;
  } else if (g < 560) { u = g - NP; v = 32; }
  else if (g == 560)  { u = 32; v = 32; }
  else                { u = 33; v = 33; }
}

// fp32 -> bf16 bits, round-to-nearest-even
__device__ __forceinline__ unsigned short f2bf(float f) {
  unsigned u = __builtin_bit_cast(unsigned, f);
  return (unsigned short)((u + 0x7FFFu + ((u >> 16) & 1u)) >> 16);
}

// ---- kernel 1: argmax + per-block partial histogram (8 blocks, no global atomics) ----
__global__ __launch_bounds__(256) void k_assign(const float* __restrict__ logits,
                                                int* __restrict__ kb,
                                                int* __restrict__ cwp) {
  __shared__ int scw[K_N];
  const int t = threadIdx.x;
  if (t < K_N) scw[t] = 0;
  __syncthreads();
  int b = blockIdx.x * 256 + t;
  const float* l = logits + (size_t)b * K_N;
  float best = l[0]; int bi = 0;
  #pragma unroll
  for (int k = 1; k < K_N; ++k) { float v = l[k]; if (v > best) { best = v; bi = k; } }
  kb[b] = bi;
  atomicAdd(&scw[bi], 1);
  __syncthreads();
  if (t < K_N) cwp[blockIdx.x * 16 + t] = scw[t];
}

// ---- kernel 2: in-block compact + inline expand + MFMA Gram + fused loss ----
__global__ __launch_bounds__(256) void k_main(const float* __restrict__ emb,
                                              const float* __restrict__ cen,
                                              const int* __restrict__ kb,
                                              const int* __restrict__ cwp,
                                              float* __restrict__ lossAcc,
                                              int* __restrict__ ctr,
                                              float* __restrict__ out) {
  const int k  = blockIdx.z;
  const int Pt = blockIdx.y, Qt = blockIdx.x;
  const int t  = threadIdx.x;
  const int wid = t >> 6, lane = t & 63;
  const int wr = wid >> 1, wc = wid & 1;
  const int lr = lane & 15, kg = lane >> 4;

  __shared__ unsigned char tI0[NCOLP], tI1[NCOLP];
  __shared__ unsigned short rl[B_N];                     // cluster row list
  __shared__ __align__(16) float sd[32][36];             // 32 diff rows (+ones,+zero)
  __shared__ __align__(16) unsigned short tiles[2][4][TILE][8]; // P/Q bf16 product tiles
  __shared__ float scen[DIM];
  __shared__ int wc4[4];
  __shared__ float sred[4];

  // prologue: decode tables, center, cluster size
  for (int c = t; c < NCOLP; c += 256) {
    int u, v; decode_col(c, u, v);
    tI0[c] = (unsigned char)u; tI1[c] = (unsigned char)v;
  }
  if (t < DIM) scen[t] = cen[k * DIM + t];
  int nb = 0;
  #pragma unroll
  for (int p = 0; p < 8; ++p) nb += cwp[p * 16 + k];
  __syncthreads();

  // in-block stream compaction: rl = sorted rows with kb[row] == k
  int base = 0;
  #pragma unroll
  for (int rd = 0; rd < 8; ++rd) {
    int e = rd * 256 + t;
    bool f = (kb[e] == k);
    unsigned long long m = __ballot(f);
    int wcnt = __popcll(m);
    int wpre = __popcll(m & ((1ull << lane) - 1ull));
    if (lane == 0) wc4[wid] = wcnt;
    __syncthreads();
    int off = base;
    for (int q = 0; q < wid; ++q) off += wc4[q];
    if (f) rl[off + wpre] = (unsigned short)e;
    base += wc4[0] + wc4[1] + wc4[2] + wc4[3];
    __syncthreads();
  }

  f32x4 acc[4][4];
  {
    f32x4 z = {0.f, 0.f, 0.f, 0.f};
    #pragma unroll
    for (int a = 0; a < 4; ++a)
      #pragma unroll
      for (int c = 0; c < 4; ++c) acc[a][c] = z;
  }

  const float4* e4 = reinterpret_cast<const float4*>(emb);

  for (int cb = 0; cb < nb; cb += 32) {
    // gather 32 diff rows (zero past nb)
    {
      int r = t >> 3, part = t & 7;
      int idx = cb + r;
      float4 v = make_float4(0.f, 0.f, 0.f, 0.f);
      if (idx < nb) {
        int g = rl[idx];
        float4 e = e4[g * 8 + part];
        v = make_float4(e.x - scen[part * 4], e.y - scen[part * 4 + 1],
                        e.z - scen[part * 4 + 2], e.w - scen[part * 4 + 3]);
      }
      *reinterpret_cast<float4*>(&sd[r][part * 4]) = v;
      if (part == 0) { sd[r][32] = (idx < nb) ? 1.f : 0.f; sd[r][33] = 0.f; }
    }
    __syncthreads();
    // products -> bf16 tiles (P side, Q side), Vt-tiled layout [side][ch][col][8]
    #pragma unroll
    for (int uu = 0; uu < 4; ++uu) {
      int unit = t + uu * 256;          // 0..1023
      int side = unit >> 9;
      int rem  = unit & 511;
      int ch = rem >> 7, col = rem & 127;
      int gcol = (side ? Qt : Pt) * TILE + col;
      int u = tI0[gcol], v = tI1[gcol];
      bf16x8 pk;
      #pragma unroll
      for (int e = 0; e < 8; ++e)
        pk[e] = (short)f2bf(sd[ch * 8 + e][u] * sd[ch * 8 + e][v]);
      *reinterpret_cast<bf16x8*>(&tiles[side][ch][col][0]) = pk;
    }
    __syncthreads();
    // fragments (same addressing as validated r8 kernel) + 16 MFMA
    bf16x8 a[4], b[4];
    #pragma unroll
    for (int f = 0; f < 4; ++f) {
      a[f] = *reinterpret_cast<const bf16x8*>(&tiles[0][kg][wr * 64 + f * 16 + lr][0]);
      b[f] = *reinterpret_cast<const bf16x8*>(&tiles[1][kg][wc * 64 + f * 16 + lr][0]);
    }
    #pragma unroll
    for (int fa = 0; fa < 4; ++fa)
      #pragma unroll
      for (int fc = 0; fc < 4; ++fc)
        acc[fa][fc] = __builtin_amdgcn_mfma_f32_16x16x32_bf16(a[fa], b[fc], acc[fa][fc], 0, 0, 0);
    __syncthreads();
  }

  // ---- fused epilogue (byte-identical algebra; validated absmax=0 r2/r5/r6/r8/r10) ----
  // C/D layout (m89-verified): Q(col) = lane&15, P(row) = (lane>>4)*4 + reg
  const int pb = Pt * TILE + wr * 64;
  const int qb = Qt * TILE + wc * 64;
  const float inv_cnt = 1.f / ((float)nb + 1e-7f);
  float sum = 0.f;
  #pragma unroll
  for (int fa = 0; fa < 4; ++fa) {
    #pragma unroll
    for (int r = 0; r < 4; ++r) {
      const int P = pb + fa * 16 + kg * 4 + r;
      const int i = tI0[P], j = tI1[P];
      #pragma unroll
      for (int fc = 0; fc < 4; ++fc) {
        const int Q = qb + fc * 16 + lr;
        const int li = tI0[Q], mi = tI1[Q];
        const float g = acc[fa][fc][r];
        if (P < NP) {
          if (Q < NP) {
            int s0 = min(i, li), x1 = max(i, li), x2 = min(j, mi), s3 = max(j, mi);
            int s1 = min(x1, x2), s2 = max(x1, x2);
            bool e01 = (s0 == s1), e12 = (s1 == s2), e23 = (s2 == s3);
            float wgt, tgt = 0.f;
            if (e01 && e12 && e23)                 wgt = 0.f;
            else if (e01 && e23)                   { wgt = 2.f / 9.f; tgt = T4C1; }
            else if ((e01 && e12) || (e12 && e23)) wgt = 0.25f;
            else if (e01 || e12 || e23)            wgt = 5.f / 24.f;
            else                                   wgt = 1.f / 6.f;
            float d = c4f(g) - tgt;
            sum += 0.125f * wgt * d * d;
          } else if (Q < 560) {
            if (Q - NP >= j) { float d = c3f(g); sum += 0.25f * d * d; }
          } else if (Q == 560) {
            if (i < j) { float d = c2f(g * inv_cnt); sum += 0.5f * d * d; }
          }
        } else if (P < 560 && Q == 560) {
          float m1 = g * inv_cnt;
          sum += m1 * m1;
        }
      }
    }
  }

  #pragma unroll
  for (int off = 32; off > 0; off >>= 1) sum += __shfl_down(sum, off, 64);
  if (lane == 0) sred[wid] = sum;
  __syncthreads();
  if (t == 0) {
    float s = sred[0] + sred[1] + sred[2] + sred[3];
    atomicAdd(lossAcc, s * ((float)nb * (1.f / (float)B_N)));
    __threadfence();
    if (atomicAdd(ctr, 1) == NBLK - 1) out[0] = atomicAdd(lossAcc, 0.f);
  }
}

extern "C" void kernel_launch(void* const* d_in, const int* in_sizes, int n_in,
                              void* d_out, int out_size, void* d_ws, size_t ws_size,
                              hipStream_t stream) {
  const float* emb = (const float*)d_in[0];
  const float* cen = (const float*)d_in[1];
  const float* lg  = (const float*)d_in[2];
  float* out = (float*)d_out;
  int*   wsi = (int*)d_ws;
  float* wsf = (float*)d_ws;

  int*   kb    = wsi + WS_KB;
  int*   cwp   = wsi + WS_CWP;
  float* lossA = wsf + WS_LOSS;
  int*   ctr   = wsi + WS_CTR;

  (void)hipMemsetAsync(d_ws, 0, 64 * 4, stream);   // loss, ctr
  k_assign<<<B_N / 256, 256, 0, stream>>>(lg, kb, cwp);
  k_main  <<<dim3(NT, NT, K_N), 256, 0, stream>>>(emb, cen, kb, cwp, lossA, ctr, out);
}

// Round 12
// 31.303 us; speedup vs baseline: 5.1402x; 1.4359x over previous
//
#include <hip/hip_runtime.h>
#include <math.h>

#define B_N 2048
#define DIM 32
#define K_N 10
#define NP  528          // sorted pairs (i<=j)
#define NCOLP 640        // padded column count (5 tiles x 128)
#define TILE 128
#define NT 5
#define NBLK (NT*NT*K_N)   // 250 blocks

typedef __attribute__((ext_vector_type(8))) short bf16x8;   // 8 bf16 = 4 VGPRs
typedef __attribute__((ext_vector_type(4))) float f32x4;    // mfma 16x16 accum

// ---- ws layout (4-byte words); memset zeroes words 0..63 each launch ----
#define WS_LOSS 0
#define WS_CTR  1
#define WS_CWP  16        // cwp[8][16] partial counts (plain stores)
#define WS_KB   160       // kb[2048] int

__device__ __forceinline__ float c2f(float x) {
  float r = sqrtf(fabsf(x) + 0.25f) - 0.5f;
  return (x >= 0.f) ? r : -r;
}
__device__ __forceinline__ float c3f(float x) {
  float v = fabsf(x) + 0.19245008973f;
  float r = exp2f(log2f(v) * 0.33333333333f) - 0.57735026919f;
  return (x >= 0.f) ? r : -r;
}
__device__ __forceinline__ float c4f(float x) {
  float r = sqrtf(sqrtf(fabsf(x) + 0.15749013123f)) - 0.62996052494f;
  return (x >= 0.f) ? r : -r;
}
#define T4C1 (sqrtf(sqrtf(1.f + 0.15749013123f)) - 0.62996052494f)

// col -> (u,v) with d[32]=1 (ones), d[33]=0 (pad)
__device__ __forceinline__ void decode_col(int g, int& u, int& v) {
  if (g < NP) {
    int j = (int)((sqrtf(8.f * (float)g + 1.f) - 1.f) * 0.5f);
    while (j * (j + 1) / 2 > g) --j;
    while ((j + 1) * (j + 2) / 2 <= g) ++j;
    u = g - j * (j + 1) / 2; v = j;
  } else if (g < 560) { u = g - NP; v = 32; }
  else if (g == 560)  { u = 32; v = 32; }
  else                { u = 33; v = 33; }
}

// fp32 -> bf16 bits, round-to-nearest-even
__device__ __forceinline__ unsigned short f2bf(float f) {
  unsigned u = __builtin_bit_cast(unsigned, f);
  return (unsigned short)((u + 0x7FFFu + ((u >> 16) & 1u)) >> 16);
}

// ---- kernel 1: argmax + per-block partial histogram (8 blocks) ----
__global__ __launch_bounds__(256) void k_assign(const float* __restrict__ logits,
                                                int* __restrict__ kb,
                                                int* __restrict__ cwp) {
  __shared__ int scw[K_N];
  const int t = threadIdx.x;
  if (t < K_N) scw[t] = 0;
  __syncthreads();
  int b = blockIdx.x * 256 + t;
  const float* l = logits + (size_t)b * K_N;
  float best = l[0]; int bi = 0;
  #pragma unroll
  for (int k = 1; k < K_N; ++k) { float v = l[k]; if (v > best) { best = v; bi = k; } }
  kb[b] = bi;
  atomicAdd(&scw[bi], 1);
  __syncthreads();
  if (t < K_N) cwp[blockIdx.x * 16 + t] = scw[t];
}

// ---- kernel 2: 1024-thread (16-wave) compact + expand + MFMA Gram + fused loss ----
__global__ __launch_bounds__(1024) void k_main(const float* __restrict__ emb,
                                               const float* __restrict__ cen,
                                               const int* __restrict__ kb,
                                               const int* __restrict__ cwp,
                                               float* __restrict__ lossAcc,
                                               int* __restrict__ ctr,
                                               float* __restrict__ out) {
  const int k  = blockIdx.z;
  const int Pt = blockIdx.y, Qt = blockIdx.x;
  const int t  = threadIdx.x;
  const int wid = t >> 6, lane = t & 63;
  const int wr = wid >> 2, wc = wid & 3;          // 4x4 wave grid over 128x128 tile
  const int lr = lane & 15, kg = lane >> 4;

  __shared__ unsigned char tI0[NCOLP], tI1[NCOLP];
  __shared__ unsigned short rl[B_N];                          // cluster row list
  __shared__ __align__(16) float sd[32][36];                  // 32 diff rows (+ones,+zero)
  __shared__ __align__(16) unsigned short tiles[2][4][TILE][8];
  __shared__ float scen[DIM];
  __shared__ int wcs[16];
  __shared__ float sred[16];

  // prologue: decode tables, center, cluster size
  if (t < NCOLP) {
    int u, v; decode_col(t, u, v);
    tI0[t] = (unsigned char)u; tI1[t] = (unsigned char)v;
  }
  if (t < DIM) scen[t] = cen[k * DIM + t];
  int nb = 0;
  #pragma unroll
  for (int p = 0; p < 8; ++p) nb += cwp[p * 16 + k];
  __syncthreads();

  // in-block stream compaction (2 rounds of 1024): rl = ascending rows with kb==k
  int base = 0;
  #pragma unroll
  for (int rd = 0; rd < 2; ++rd) {
    int e = rd * 1024 + t;
    bool f = (kb[e] == k);
    unsigned long long m = __ballot(f);
    int wpre = __popcll(m & ((1ull << lane) - 1ull));
    if (lane == 0) wcs[wid] = __popcll(m);
    __syncthreads();
    int off = base;
    for (int q = 0; q < wid; ++q) off += wcs[q];
    if (f) rl[off + wpre] = (unsigned short)e;
    int tot = 0;
    #pragma unroll
    for (int q = 0; q < 16; ++q) tot += wcs[q];
    base += tot;
    __syncthreads();
  }

  f32x4 acc[2][2];
  {
    f32x4 z = {0.f, 0.f, 0.f, 0.f};
    acc[0][0] = z; acc[0][1] = z; acc[1][0] = z; acc[1][1] = z;
  }

  const float4* e4 = reinterpret_cast<const float4*>(emb);

  for (int cb = 0; cb < nb; cb += 32) {
    // gather 32 diff rows (zero past nb)
    if (t < 256) {
      int r = t >> 3, part = t & 7;
      int idx = cb + r;
      float4 v = make_float4(0.f, 0.f, 0.f, 0.f);
      if (idx < nb) {
        int g = rl[idx];
        float4 e = e4[g * 8 + part];
        v = make_float4(e.x - scen[part * 4], e.y - scen[part * 4 + 1],
                        e.z - scen[part * 4 + 2], e.w - scen[part * 4 + 3]);
      }
      *reinterpret_cast<float4*>(&sd[r][part * 4]) = v;
      if (part == 0) { sd[r][32] = (idx < nb) ? 1.f : 0.f; sd[r][33] = 0.f; }
    }
    __syncthreads();
    // products -> bf16 tiles; one bf16x8 unit per thread
    {
      int side = t >> 9;                // 0 = P side, 1 = Q side
      int rem  = t & 511;
      int ch = rem >> 7, col = rem & 127;
      int gcol = (side ? Qt : Pt) * TILE + col;
      int u = tI0[gcol], v = tI1[gcol];
      bf16x8 pk;
      #pragma unroll
      for (int e = 0; e < 8; ++e)
        pk[e] = (short)f2bf(sd[ch * 8 + e][u] * sd[ch * 8 + e][v]);
      *reinterpret_cast<bf16x8*>(&tiles[side][ch][col][0]) = pk;
    }
    __syncthreads();
    // fragments (same addressing family as validated r8/r11) + 4 MFMA per wave
    bf16x8 a[2], b[2];
    #pragma unroll
    for (int f = 0; f < 2; ++f) {
      a[f] = *reinterpret_cast<const bf16x8*>(&tiles[0][kg][wr * 32 + f * 16 + lr][0]);
      b[f] = *reinterpret_cast<const bf16x8*>(&tiles[1][kg][wc * 32 + f * 16 + lr][0]);
    }
    #pragma unroll
    for (int fa = 0; fa < 2; ++fa)
      #pragma unroll
      for (int fc = 0; fc < 2; ++fc)
        acc[fa][fc] = __builtin_amdgcn_mfma_f32_16x16x32_bf16(a[fa], b[fc], acc[fa][fc], 0, 0, 0);
    __syncthreads();
  }

  // ---- fused epilogue (same algebra; validated absmax=0 r2/r5/r6/r8/r10/r11) ----
  // C/D layout (m89-verified): Q(col) = lane&15, P(row) = (lane>>4)*4 + reg
  const int pb = Pt * TILE + wr * 32;
  const int qb = Qt * TILE + wc * 32;
  const float inv_cnt = 1.f / ((float)nb + 1e-7f);
  float sum = 0.f;
  #pragma unroll
  for (int fa = 0; fa < 2; ++fa) {
    #pragma unroll
    for (int r = 0; r < 4; ++r) {
      const int P = pb + fa * 16 + kg * 4 + r;
      const int i = tI0[P], j = tI1[P];
      #pragma unroll
      for (int fc = 0; fc < 2; ++fc) {
        const int Q = qb + fc * 16 + lr;
        const int li = tI0[Q], mi = tI1[Q];
        const float g = acc[fa][fc][r];
        if (P < NP) {
          if (Q < NP) {
            int s0 = min(i, li), x1 = max(i, li), x2 = min(j, mi), s3 = max(j, mi);
            int s1 = min(x1, x2), s2 = max(x1, x2);
            bool e01 = (s0 == s1), e12 = (s1 == s2), e23 = (s2 == s3);
            float wgt, tgt = 0.f;
            if (e01 && e12 && e23)                 wgt = 0.f;
            else if (e01 && e23)                   { wgt = 2.f / 9.f; tgt = T4C1; }
            else if ((e01 && e12) || (e12 && e23)) wgt = 0.25f;
            else if (e01 || e12 || e23)            wgt = 5.f / 24.f;
            else                                   wgt = 1.f / 6.f;
            float d = c4f(g) - tgt;
            sum += 0.125f * wgt * d * d;
          } else if (Q < 560) {
            if (Q - NP >= j) { float d = c3f(g); sum += 0.25f * d * d; }
          } else if (Q == 560) {
            if (i < j) { float d = c2f(g * inv_cnt); sum += 0.5f * d * d; }
          }
        } else if (P < 560 && Q == 560) {
          float m1 = g * inv_cnt;
          sum += m1 * m1;
        }
      }
    }
  }

  #pragma unroll
  for (int off = 32; off > 0; off >>= 1) sum += __shfl_down(sum, off, 64);
  if (lane == 0) sred[wid] = sum;
  __syncthreads();
  if (t == 0) {
    float s = 0.f;
    #pragma unroll
    for (int q = 0; q < 16; ++q) s += sred[q];
    atomicAdd(lossAcc, s * ((float)nb * (1.f / (float)B_N)));
    __threadfence();
    if (atomicAdd(ctr, 1) == NBLK - 1) out[0] = atomicAdd(lossAcc, 0.f);
  }
}

extern "C" void kernel_launch(void* const* d_in, const int* in_sizes, int n_in,
                              void* d_out, int out_size, void* d_ws, size_t ws_size,
                              hipStream_t stream) {
  const float* emb = (const float*)d_in[0];
  const float* cen = (const float*)d_in[1];
  const float* lg  = (const float*)d_in[2];
  float* out = (float*)d_out;
  int*   wsi = (int*)d_ws;
  float* wsf = (float*)d_ws;

  int*   kb    = wsi + WS_KB;
  int*   cwp   = wsi + WS_CWP;
  float* lossA = wsf + WS_LOSS;
  int*   ctr   = wsi + WS_CTR;

  (void)hipMemsetAsync(d_ws, 0, 64 * 4, stream);   // loss, ctr
  k_assign<<<B_N / 256, 256, 0, stream>>>(lg, kb, cwp);
  k_main  <<<dim3(NT, NT, K_N), 1024, 0, stream>>>(emb, cen, kb, cwp, lossA, ctr, out);
}

// Round 13
// 28.880 us; speedup vs baseline: 5.5713x; 1.0839x over previous
//
#include <hip/hip_runtime.h>
#include <math.h>

#define B_N 2048
#define DIM 32
#define K_N 10
#define NP  528          // sorted pairs (i<=j)
#define NCOLP 640        // padded column count (5 tiles x 128)
#define TILE 128
#define NT 5
#define NBLK (NT*NT*K_N)   // 250 blocks
#define CH 64              // samples per chunk

typedef __attribute__((ext_vector_type(8))) short bf16x8;   // 8 bf16 = 4 VGPRs
typedef __attribute__((ext_vector_type(4))) float f32x4;    // mfma 16x16 accum

// ---- ws layout (4-byte words); memset zeroes words 0..63 each launch ----
#define WS_LOSS 0
#define WS_CTR  1

__device__ __forceinline__ float c2f(float x) {
  float r = sqrtf(fabsf(x) + 0.25f) - 0.5f;
  return (x >= 0.f) ? r : -r;
}
__device__ __forceinline__ float c3f(float x) {
  float v = fabsf(x) + 0.19245008973f;
  float r = exp2f(log2f(v) * 0.33333333333f) - 0.57735026919f;
  return (x >= 0.f) ? r : -r;
}
__device__ __forceinline__ float c4f(float x) {
  float r = sqrtf(sqrtf(fabsf(x) + 0.15749013123f)) - 0.62996052494f;
  return (x >= 0.f) ? r : -r;
}
#define T4C1 (sqrtf(sqrtf(1.f + 0.15749013123f)) - 0.62996052494f)

// col -> (u,v) with d[32]=1 (ones), d[33]=0 (pad)
__device__ __forceinline__ void decode_col(int g, int& u, int& v) {
  if (g < NP) {
    int j = (int)((sqrtf(8.f * (float)g + 1.f) - 1.f) * 0.5f);
    while (j * (j + 1) / 2 > g) --j;
    while ((j + 1) * (j + 2) / 2 <= g) ++j;
    u = g - j * (j + 1) / 2; v = j;
  } else if (g < 560) { u = g - NP; v = 32; }
  else if (g == 560)  { u = 32; v = 32; }
  else                { u = 33; v = 33; }
}

// fp32 -> bf16 bits, round-to-nearest-even
__device__ __forceinline__ unsigned short f2bf(float f) {
  unsigned u = __builtin_bit_cast(unsigned, f);
  return (unsigned short)((u + 0x7FFFu + ((u >> 16) & 1u)) >> 16);
}

// ---- single compute kernel: argmax + compact + expand + MFMA Gram + fused loss ----
__global__ __launch_bounds__(1024) void k_main(const float* __restrict__ emb,
                                               const float* __restrict__ cen,
                                               const float* __restrict__ lg,
                                               float* __restrict__ lossAcc,
                                               int* __restrict__ ctr,
                                               float* __restrict__ out) {
  const int k  = blockIdx.z;
  const int Pt = blockIdx.y, Qt = blockIdx.x;
  const int t  = threadIdx.x;
  const int wid = t >> 6, lane = t & 63;
  const int wr = wid >> 2, wc = wid & 3;          // 4x4 wave grid over 128x128 tile
  const int lr = lane & 15, kg = lane >> 4;

  __shared__ unsigned char tI0[NCOLP], tI1[NCOLP];
  __shared__ short skb[B_N];                      // per-block argmax result
  __shared__ unsigned short rl[B_N];              // cluster row list
  __shared__ __align__(16) float sd[CH][36];      // CH diff rows (+ones,+zero)
  __shared__ __align__(16) unsigned short tiles[2][8][TILE][8];
  __shared__ float scen[DIM];
  __shared__ int wcs[16];
  __shared__ float sred[16];

  // ---- prologue: decode tables, center, in-block argmax ----
  if (t < NCOLP) {
    int u, v; decode_col(t, u, v);
    tI0[t] = (unsigned char)u; tI1[t] = (unsigned char)v;
  }
  if (t < DIM) scen[t] = cen[k * DIM + t];
  #pragma unroll
  for (int rd = 0; rd < 2; ++rd) {
    int b = rd * 1024 + t;
    const float* l = lg + (size_t)b * K_N;
    float best = l[0]; int bi = 0;
    #pragma unroll
    for (int q = 1; q < K_N; ++q) { float v = l[q]; if (v > best) { best = v; bi = q; } }
    skb[b] = (short)bi;
  }
  __syncthreads();

  // ---- in-block stream compaction: rl = ascending rows with skb==k; nb = count ----
  int nb = 0;
  #pragma unroll
  for (int rd = 0; rd < 2; ++rd) {
    int e = rd * 1024 + t;
    bool f = (skb[e] == (short)k);
    unsigned long long m = __ballot(f);
    int wpre = __popcll(m & ((1ull << lane) - 1ull));
    if (lane == 0) wcs[wid] = __popcll(m);
    __syncthreads();
    int off = nb;
    for (int q = 0; q < wid; ++q) off += wcs[q];
    if (f) rl[off + wpre] = (unsigned short)e;
    int tot = 0;
    #pragma unroll
    for (int q = 0; q < 16; ++q) tot += wcs[q];
    nb += tot;
    __syncthreads();
  }

  f32x4 acc[2][2];
  {
    f32x4 z = {0.f, 0.f, 0.f, 0.f};
    acc[0][0] = z; acc[0][1] = z; acc[1][0] = z; acc[1][1] = z;
  }

  const float4* e4 = reinterpret_cast<const float4*>(emb);
  const int gr = t >> 3, gpart = t & 7;           // gather role (t < 512)

  // prefetch chunk 0
  float4 pf = make_float4(0.f, 0.f, 0.f, 0.f);
  bool pvalid = false;
  if (t < 512) {
    int idx = gr;
    pvalid = (idx < nb);
    if (pvalid) {
      float4 e = e4[rl[idx] * 8 + gpart];
      pf = make_float4(e.x - scen[gpart * 4], e.y - scen[gpart * 4 + 1],
                       e.z - scen[gpart * 4 + 2], e.w - scen[gpart * 4 + 3]);
    }
  }

  for (int cb = 0; cb < nb; cb += CH) {
    // write prefetched diff rows to LDS
    if (t < 512) {
      *reinterpret_cast<float4*>(&sd[gr][gpart * 4]) = pf;
      if (gpart == 0) { sd[gr][32] = pvalid ? 1.f : 0.f; sd[gr][33] = 0.f; }
    }
    __syncthreads();
    // issue next chunk's gather (latency hides under expand + MFMA)
    if (t < 512) {
      int idx = cb + CH + gr;
      pvalid = (idx < nb);
      pf = make_float4(0.f, 0.f, 0.f, 0.f);
      if (pvalid) {
        float4 e = e4[rl[idx] * 8 + gpart];
        pf = make_float4(e.x - scen[gpart * 4], e.y - scen[gpart * 4 + 1],
                         e.z - scen[gpart * 4 + 2], e.w - scen[gpart * 4 + 3]);
      }
    }
    // expand: 2 bf16x8 units per thread (2048 units = 2 sides x 8 ch x 128 cols)
    #pragma unroll
    for (int uu = 0; uu < 2; ++uu) {
      int unit = t + uu * 1024;
      int side = unit >> 10;
      int rem  = unit & 1023;
      int ch = rem >> 7, col = rem & 127;
      int gcol = (side ? Qt : Pt) * TILE + col;
      int u = tI0[gcol], v = tI1[gcol];
      bf16x8 pk;
      #pragma unroll
      for (int e = 0; e < 8; ++e)
        pk[e] = (short)f2bf(sd[ch * 8 + e][u] * sd[ch * 8 + e][v]);
      *reinterpret_cast<bf16x8*>(&tiles[side][ch][col][0]) = pk;
    }
    __syncthreads();
    // 2 K-steps x 4 MFMA per wave (fragment addressing family validated r8-r12)
    #pragma unroll
    for (int s = 0; s < 2; ++s) {
      bf16x8 a[2], b[2];
      #pragma unroll
      for (int f = 0; f < 2; ++f) {
        a[f] = *reinterpret_cast<const bf16x8*>(&tiles[0][s * 4 + kg][wr * 32 + f * 16 + lr][0]);
        b[f] = *reinterpret_cast<const bf16x8*>(&tiles[1][s * 4 + kg][wc * 32 + f * 16 + lr][0]);
      }
      #pragma unroll
      for (int fa = 0; fa < 2; ++fa)
        #pragma unroll
        for (int fc = 0; fc < 2; ++fc)
          acc[fa][fc] = __builtin_amdgcn_mfma_f32_16x16x32_bf16(a[fa], b[fc], acc[fa][fc], 0, 0, 0);
    }
    __syncthreads();
  }

  // ---- fused epilogue (same algebra; validated absmax=0 r2/r5/r6/r8/r10/r11/r12) ----
  // C/D layout (m89-verified): Q(col) = lane&15, P(row) = (lane>>4)*4 + reg
  const int pb = Pt * TILE + wr * 32;
  const int qb = Qt * TILE + wc * 32;
  const float inv_cnt = 1.f / ((float)nb + 1e-7f);
  float sum = 0.f;
  #pragma unroll
  for (int fa = 0; fa < 2; ++fa) {
    #pragma unroll
    for (int r = 0; r < 4; ++r) {
      const int P = pb + fa * 16 + kg * 4 + r;
      const int i = tI0[P], j = tI1[P];
      #pragma unroll
      for (int fc = 0; fc < 2; ++fc) {
        const int Q = qb + fc * 16 + lr;
        const int li = tI0[Q], mi = tI1[Q];
        const float g = acc[fa][fc][r];
        if (P < NP) {
          if (Q < NP) {
            int s0 = min(i, li), x1 = max(i, li), x2 = min(j, mi), s3 = max(j, mi);
            int s1 = min(x1, x2), s2 = max(x1, x2);
            bool e01 = (s0 == s1), e12 = (s1 == s2), e23 = (s2 == s3);
            float wgt, tgt = 0.f;
            if (e01 && e12 && e23)                 wgt = 0.f;
            else if (e01 && e23)                   { wgt = 2.f / 9.f; tgt = T4C1; }
            else if ((e01 && e12) || (e12 && e23)) wgt = 0.25f;
            else if (e01 || e12 || e23)            wgt = 5.f / 24.f;
            else                                   wgt = 1.f / 6.f;
            float d = c4f(g) - tgt;
            sum += 0.125f * wgt * d * d;
          } else if (Q < 560) {
            if (Q - NP >= j) { float d = c3f(g); sum += 0.25f * d * d; }
          } else if (Q == 560) {
            if (i < j) { float d = c2f(g * inv_cnt); sum += 0.5f * d * d; }
          }
        } else if (P < 560 && Q == 560) {
          float m1 = g * inv_cnt;
          sum += m1 * m1;
        }
      }
    }
  }

  #pragma unroll
  for (int off = 32; off > 0; off >>= 1) sum += __shfl_down(sum, off, 64);
  if (lane == 0) sred[wid] = sum;
  __syncthreads();
  if (t == 0) {
    float s = 0.f;
    #pragma unroll
    for (int q = 0; q < 16; ++q) s += sred[q];
    atomicAdd(lossAcc, s * ((float)nb * (1.f / (float)B_N)));
    __threadfence();
    if (atomicAdd(ctr, 1) == NBLK - 1) out[0] = atomicAdd(lossAcc, 0.f);
  }
}

extern "C" void kernel_launch(void* const* d_in, const int* in_sizes, int n_in,
                              void* d_out, int out_size, void* d_ws, size_t ws_size,
                              hipStream_t stream) {
  const float* emb = (const float*)d_in[0];
  const float* cen = (const float*)d_in[1];
  const float* lg  = (const float*)d_in[2];
  float* out = (float*)d_out;
  float* wsf = (float*)d_ws;
  int*   wsi = (int*)d_ws;

  float* lossA = wsf + WS_LOSS;
  int*   ctr   = wsi + WS_CTR;

  (void)hipMemsetAsync(d_ws, 0, 64 * 4, stream);   // loss, ctr
  k_main<<<dim3(NT, NT, K_N), 1024, 0, stream>>>(emb, cen, lg, lossA, ctr, out);
}

// Round 14
// 28.778 us; speedup vs baseline: 5.5913x; 1.0036x over previous
//
#include <hip/hip_runtime.h>
#include <math.h>

#define B_N 2048
#define DIM 32
#define K_N 10
#define NP  528          // sorted pairs (i<=j)
#define NCOLP 640        // padded column count (5 tiles x 128)
#define TILE 128
#define NT 5
#define NBLK (NT*NT*K_N)   // 250 blocks
#define CH 64              // samples per chunk
#define SDST 68            // sdT row stride (floats): 16B-aligned, 4-way write conflicts

typedef __attribute__((ext_vector_type(8))) short bf16x8;   // 8 bf16 = 4 VGPRs
typedef __attribute__((ext_vector_type(4))) float f32x4;    // mfma 16x16 accum

// ---- ws layout (4-byte words); memset zeroes words 0..63 each launch ----
#define WS_LOSS 0
#define WS_CTR  1

__device__ __forceinline__ float c2f(float x) {
  float r = sqrtf(fabsf(x) + 0.25f) - 0.5f;
  return (x >= 0.f) ? r : -r;
}
__device__ __forceinline__ float c3f(float x) {
  float v = fabsf(x) + 0.19245008973f;
  float r = exp2f(log2f(v) * 0.33333333333f) - 0.57735026919f;
  return (x >= 0.f) ? r : -r;
}
__device__ __forceinline__ float c4f(float x) {
  float r = sqrtf(sqrtf(fabsf(x) + 0.15749013123f)) - 0.62996052494f;
  return (x >= 0.f) ? r : -r;
}
#define T4C1 (sqrtf(sqrtf(1.f + 0.15749013123f)) - 0.62996052494f)

// col -> (u,v) with d[32]=1 (ones), d[33]=0 (pad)
__device__ __forceinline__ void decode_col(int g, int& u, int& v) {
  if (g < NP) {
    int j = (int)((sqrtf(8.f * (float)g + 1.f) - 1.f) * 0.5f);
    while (j * (j + 1) / 2 > g) --j;
    while ((j + 1) * (j + 2) / 2 <= g) ++j;
    u = g - j * (j + 1) / 2; v = j;
  } else if (g < 560) { u = g - NP; v = 32; }
  else if (g == 560)  { u = 32; v = 32; }
  else                { u = 33; v = 33; }
}

// fp32 -> bf16 bits, round-to-nearest-even
__device__ __forceinline__ unsigned short f2bf(float f) {
  unsigned u = __builtin_bit_cast(unsigned, f);
  return (unsigned short)((u + 0x7FFFu + ((u >> 16) & 1u)) >> 16);
}

// ---- single compute kernel: argmax + compact + expand + MFMA Gram + fused loss ----
__global__ __launch_bounds__(1024) void k_main(const float* __restrict__ emb,
                                               const float* __restrict__ cen,
                                               const float* __restrict__ lg,
                                               float* __restrict__ lossAcc,
                                               int* __restrict__ ctr,
                                               float* __restrict__ out) {
  const int k  = blockIdx.z;
  const int Pt = blockIdx.y, Qt = blockIdx.x;
  const int t  = threadIdx.x;
  const int wid = t >> 6, lane = t & 63;
  const int wr = wid >> 2, wc = wid & 3;          // 4x4 wave grid over 128x128 tile
  const int lr = lane & 15, kg = lane >> 4;

  __shared__ unsigned char tI0[NCOLP], tI1[NCOLP];
  __shared__ unsigned short rl[B_N];                       // cluster row list
  __shared__ __align__(16) float sdT[34][SDST];            // dim-major diff (+ones,+zero)
  __shared__ __align__(16) unsigned short tiles[2][2][8][TILE][8]; // [buf][side][ch][col][8]
  __shared__ float scen[DIM];
  __shared__ int wcs[16];
  __shared__ float sred[16];

  // ---- prologue: decode tables, center ----
  if (t < NCOLP) {
    int u, v; decode_col(t, u, v);
    tI0[t] = (unsigned char)u; tI1[t] = (unsigned char)v;
  }
  if (t < DIM) scen[t] = cen[k * DIM + t];
  __syncthreads();

  // ---- fused argmax + in-block compaction: rl = ascending rows with argmax==k ----
  int nb = 0;
  #pragma unroll
  for (int rd = 0; rd < 2; ++rd) {
    int e = rd * 1024 + t;
    const float* l = lg + (size_t)e * K_N;
    float best = l[0]; int bi = 0;
    #pragma unroll
    for (int q = 1; q < K_N; ++q) { float v = l[q]; if (v > best) { best = v; bi = q; } }
    bool f = (bi == k);
    unsigned long long m = __ballot(f);
    int wpre = __popcll(m & ((1ull << lane) - 1ull));
    if (lane == 0) wcs[wid] = __popcll(m);
    __syncthreads();
    int off = nb;
    for (int q = 0; q < wid; ++q) off += wcs[q];
    if (f) rl[off + wpre] = (unsigned short)e;
    int tot = 0;
    #pragma unroll
    for (int q = 0; q < 16; ++q) tot += wcs[q];
    nb += tot;
    __syncthreads();
  }

  f32x4 acc[2][2];
  {
    f32x4 z = {0.f, 0.f, 0.f, 0.f};
    acc[0][0] = z; acc[0][1] = z; acc[1][0] = z; acc[1][1] = z;
  }

  const float4* e4 = reinterpret_cast<const float4*>(emb);
  const int gr = t >> 3, gpart = t & 7;           // gather role (t < 512)

  // prefetch chunk 0
  float4 pf = make_float4(0.f, 0.f, 0.f, 0.f);
  bool pvalid = false;
  if (t < 512) {
    pvalid = (gr < nb);
    if (pvalid) {
      float4 e = e4[rl[gr] * 8 + gpart];
      pf = make_float4(e.x - scen[gpart * 4], e.y - scen[gpart * 4 + 1],
                       e.z - scen[gpart * 4 + 2], e.w - scen[gpart * 4 + 3]);
    }
  }

  int pp = 0;
  for (int cb = 0; cb < nb; cb += CH, pp ^= 1) {
    // write prefetched diff rows to transposed LDS
    if (t < 512) {
      sdT[gpart * 4 + 0][gr] = pf.x;
      sdT[gpart * 4 + 1][gr] = pf.y;
      sdT[gpart * 4 + 2][gr] = pf.z;
      sdT[gpart * 4 + 3][gr] = pf.w;
      if (gpart == 0) { sdT[32][gr] = pvalid ? 1.f : 0.f; sdT[33][gr] = 0.f; }
    }
    __syncthreads();
    // issue next chunk's gather (latency hides under expand + MFMA)
    if (t < 512) {
      int idx = cb + CH + gr;
      pvalid = (idx < nb);
      pf = make_float4(0.f, 0.f, 0.f, 0.f);
      if (pvalid) {
        float4 e = e4[rl[idx] * 8 + gpart];
        pf = make_float4(e.x - scen[gpart * 4], e.y - scen[gpart * 4 + 1],
                         e.z - scen[gpart * 4 + 2], e.w - scen[gpart * 4 + 3]);
      }
    }
    // expand: 2 bf16x8 units per thread; vector b128 LDS reads from sdT
    #pragma unroll
    for (int uu = 0; uu < 2; ++uu) {
      int unit = t + uu * 1024;
      int side = unit >> 10;
      int rem  = unit & 1023;
      int ch = rem >> 7, col = rem & 127;
      int gcol = (side ? Qt : Pt) * TILE + col;
      int u = tI0[gcol], v = tI1[gcol];
      const float4* pu = reinterpret_cast<const float4*>(&sdT[u][ch * 8]);
      const float4* pv = reinterpret_cast<const float4*>(&sdT[v][ch * 8]);
      float4 u0 = pu[0], u1 = pu[1], v0 = pv[0], v1 = pv[1];
      bf16x8 pk;
      pk[0] = (short)f2bf(u0.x * v0.x); pk[1] = (short)f2bf(u0.y * v0.y);
      pk[2] = (short)f2bf(u0.z * v0.z); pk[3] = (short)f2bf(u0.w * v0.w);
      pk[4] = (short)f2bf(u1.x * v1.x); pk[5] = (short)f2bf(u1.y * v1.y);
      pk[6] = (short)f2bf(u1.z * v1.z); pk[7] = (short)f2bf(u1.w * v1.w);
      *reinterpret_cast<bf16x8*>(&tiles[pp][side][ch][col][0]) = pk;
    }
    __syncthreads();
    // 2 K-steps x 4 MFMA per wave (fragment addressing family validated r8-r13);
    // no trailing barrier: next chunk writes tiles[pp^1] and sdT (already read)
    #pragma unroll
    for (int s = 0; s < 2; ++s) {
      bf16x8 a[2], b[2];
      #pragma unroll
      for (int f = 0; f < 2; ++f) {
        a[f] = *reinterpret_cast<const bf16x8*>(&tiles[pp][0][s * 4 + kg][wr * 32 + f * 16 + lr][0]);
        b[f] = *reinterpret_cast<const bf16x8*>(&tiles[pp][1][s * 4 + kg][wc * 32 + f * 16 + lr][0]);
      }
      #pragma unroll
      for (int fa = 0; fa < 2; ++fa)
        #pragma unroll
        for (int fc = 0; fc < 2; ++fc)
          acc[fa][fc] = __builtin_amdgcn_mfma_f32_16x16x32_bf16(a[fa], b[fc], acc[fa][fc], 0, 0, 0);
    }
  }
  __syncthreads();

  // ---- fused epilogue (same algebra; validated absmax=0 r2/r5/r6/r8/r10-r13) ----
  // C/D layout (m89-verified): Q(col) = lane&15, P(row) = (lane>>4)*4 + reg
  const int pb = Pt * TILE + wr * 32;
  const int qb = Qt * TILE + wc * 32;
  const float inv_cnt = 1.f / ((float)nb + 1e-7f);
  float sum = 0.f;
  #pragma unroll
  for (int fa = 0; fa < 2; ++fa) {
    #pragma unroll
    for (int r = 0; r < 4; ++r) {
      const int P = pb + fa * 16 + kg * 4 + r;
      const int i = tI0[P], j = tI1[P];
      #pragma unroll
      for (int fc = 0; fc < 2; ++fc) {
        const int Q = qb + fc * 16 + lr;
        const int li = tI0[Q], mi = tI1[Q];
        const float g = acc[fa][fc][r];
        if (P < NP) {
          if (Q < NP) {
            int s0 = min(i, li), x1 = max(i, li), x2 = min(j, mi), s3 = max(j, mi);
            int s1 = min(x1, x2), s2 = max(x1, x2);
            bool e01 = (s0 == s1), e12 = (s1 == s2), e23 = (s2 == s3);
            float wgt, tgt = 0.f;
            if (e01 && e12 && e23)                 wgt = 0.f;
            else if (e01 && e23)                   { wgt = 2.f / 9.f; tgt = T4C1; }
            else if ((e01 && e12) || (e12 && e23)) wgt = 0.25f;
            else if (e01 || e12 || e23)            wgt = 5.f / 24.f;
            else                                   wgt = 1.f / 6.f;
            float d = c4f(g) - tgt;
            sum += 0.125f * wgt * d * d;
          } else if (Q < 560) {
            if (Q - NP >= j) { float d = c3f(g); sum += 0.25f * d * d; }
          } else if (Q == 560) {
            if (i < j) { float d = c2f(g * inv_cnt); sum += 0.5f * d * d; }
          }
        } else if (P < 560 && Q == 560) {
          float m1 = g * inv_cnt;
          sum += m1 * m1;
        }
      }
    }
  }

  #pragma unroll
  for (int off = 32; off > 0; off >>= 1) sum += __shfl_down(sum, off, 64);
  if (lane == 0) sred[wid] = sum;
  __syncthreads();
  if (t == 0) {
    float s = 0.f;
    #pragma unroll
    for (int q = 0; q < 16; ++q) s += sred[q];
    atomicAdd(lossAcc, s * ((float)nb * (1.f / (float)B_N)));
    __threadfence();
    if (atomicAdd(ctr, 1) == NBLK - 1) out[0] = atomicAdd(lossAcc, 0.f);
  }
}

extern "C" void kernel_launch(void* const* d_in, const int* in_sizes, int n_in,
                              void* d_out, int out_size, void* d_ws, size_t ws_size,
                              hipStream_t stream) {
  const float* emb = (const float*)d_in[0];
  const float* cen = (const float*)d_in[1];
  const float* lg  = (const float*)d_in[2];
  float* out = (float*)d_out;
  float* wsf = (float*)d_ws;
  int*   wsi = (int*)d_ws;

  float* lossA = wsf + WS_LOSS;
  int*   ctr   = wsi + WS_CTR;

  (void)hipMemsetAsync(d_ws, 0, 64 * 4, stream);   // loss, ctr
  k_main<<<dim3(NT, NT, K_N), 1024, 0, stream>>>(emb, cen, lg, lossA, ctr, out);
}

// Round 15
// 25.968 us; speedup vs baseline: 6.1963x; 1.1082x over previous
//
#include <hip/hip_runtime.h>
#include <math.h>

#define B_N 2048
#define DIM 32
#define K_N 10
#define NP  528          // sorted pairs (i<=j)
#define NCOLP 640        // padded column count (5 tiles x 128)
#define TILE 128
#define NT 5
#define NBLK (NT*NT*K_N)   // 250 blocks
#define CH 64              // samples per chunk
#define SDST 68            // sdT row stride (floats)

typedef __attribute__((ext_vector_type(8))) short bf16x8;   // 8 bf16 = 4 VGPRs
typedef __attribute__((ext_vector_type(4))) float f32x4;    // mfma 16x16 accum

__device__ __forceinline__ float c2f(float x) {
  float r = sqrtf(fabsf(x) + 0.25f) - 0.5f;
  return (x >= 0.f) ? r : -r;
}
__device__ __forceinline__ float c3f(float x) {
  float v = fabsf(x) + 0.19245008973f;
  float r = exp2f(log2f(v) * 0.33333333333f) - 0.57735026919f;
  return (x >= 0.f) ? r : -r;
}
__device__ __forceinline__ float c4f(float x) {
  float r = sqrtf(sqrtf(fabsf(x) + 0.15749013123f)) - 0.62996052494f;
  return (x >= 0.f) ? r : -r;
}
#define T4C1 (sqrtf(sqrtf(1.f + 0.15749013123f)) - 0.62996052494f)

// col -> (u,v) with d[32]=1 (ones), d[33]=0 (pad)
__device__ __forceinline__ void decode_col(int g, int& u, int& v) {
  if (g < NP) {
    int j = (int)((sqrtf(8.f * (float)g + 1.f) - 1.f) * 0.5f);
    while (j * (j + 1) / 2 > g) --j;
    while ((j + 1) * (j + 2) / 2 <= g) ++j;
    u = g - j * (j + 1) / 2; v = j;
  } else if (g < 560) { u = g - NP; v = 32; }
  else if (g == 560)  { u = 32; v = 32; }
  else                { u = 33; v = 33; }
}

// fp32 -> bf16 bits, round-to-nearest-even
__device__ __forceinline__ unsigned short f2bf(float f) {
  unsigned u = __builtin_bit_cast(unsigned, f);
  return (unsigned short)((u + 0x7FFFu + ((u >> 16) & 1u)) >> 16);
}

// ---- single compute kernel: argmax + compact + expand + MFMA Gram + fused loss ----
__global__ __launch_bounds__(1024) void k_main(const float* __restrict__ emb,
                                               const float* __restrict__ cen,
                                               const float* __restrict__ lg,
                                               float* __restrict__ out) {
  const int k  = blockIdx.z;
  const int Pt = blockIdx.y, Qt = blockIdx.x;
  const int t  = threadIdx.x;
  const int wid = t >> 6, lane = t & 63;
  const int wr = wid >> 2, wc = wid & 3;          // 4x4 wave grid over 128x128 tile
  const int lr = lane & 15, kg = lane >> 4;

  __shared__ unsigned char tI0[NCOLP], tI1[NCOLP];
  __shared__ unsigned short rl[B_N];                       // cluster row list
  __shared__ __align__(16) float sdT[34][SDST];            // dim-major diff (+ones,+zero)
  __shared__ __align__(16) unsigned short tiles[2][2][8][TILE][8]; // [buf][side][ch][col][8]
  __shared__ float scen[DIM];
  __shared__ int wcs[32];
  __shared__ float sred[16];

  // ---- prologue: tables + both argmax rounds before any barrier ----
  if (t < NCOLP) {
    int u, v; decode_col(t, u, v);
    tI0[t] = (unsigned char)u; tI1[t] = (unsigned char)v;
  }
  if (t < DIM) scen[t] = cen[k * DIM + t];

  const int e0 = t, e1 = 1024 + t;
  const float* l0 = lg + (size_t)e0 * K_N;
  const float* l1 = lg + (size_t)e1 * K_N;
  float b0 = l0[0], b1 = l1[0];
  int i0 = 0, i1 = 0;
  #pragma unroll
  for (int q = 1; q < K_N; ++q) {
    float v0 = l0[q]; if (v0 > b0) { b0 = v0; i0 = q; }
    float v1 = l1[q]; if (v1 > b1) { b1 = v1; i1 = q; }
  }
  const bool f0 = (i0 == k), f1 = (i1 == k);
  unsigned long long m0 = __ballot(f0);
  unsigned long long m1 = __ballot(f1);
  int pre0 = __popcll(m0 & ((1ull << lane) - 1ull));
  int pre1 = __popcll(m1 & ((1ull << lane) - 1ull));
  if (lane == 0) { wcs[wid] = __popcll(m0); wcs[16 + wid] = __popcll(m1); }
  __syncthreads();                                         // barrier A
  int off0 = 0, total0 = 0, off1 = 0, nb = 0;
  #pragma unroll
  for (int q = 0; q < 16; ++q) {
    int c0 = wcs[q], c1 = wcs[16 + q];
    if (q < wid) { off0 += c0; off1 += c1; }
    total0 += c0; nb += c1;
  }
  off1 += total0; nb += total0;
  if (f0) rl[off0 + pre0] = (unsigned short)e0;
  if (f1) rl[off1 + pre1] = (unsigned short)e1;
  __syncthreads();                                         // barrier B: rl ready

  f32x4 acc[2][2];
  {
    f32x4 z = {0.f, 0.f, 0.f, 0.f};
    acc[0][0] = z; acc[0][1] = z; acc[1][0] = z; acc[1][1] = z;
  }

  const float4* e4 = reinterpret_cast<const float4*>(emb);
  const int gr = t >> 3, gpart = t & 7;           // gather role (t < 512)

  // prefetch chunk 0
  float4 pf = make_float4(0.f, 0.f, 0.f, 0.f);
  bool pvalid = false;
  if (t < 512) {
    pvalid = (gr < nb);
    if (pvalid) {
      float4 e = e4[rl[gr] * 8 + gpart];
      pf = make_float4(e.x - scen[gpart * 4], e.y - scen[gpart * 4 + 1],
                       e.z - scen[gpart * 4 + 2], e.w - scen[gpart * 4 + 3]);
    }
  }

  int pp = 0;
  for (int cb = 0; cb < nb; cb += CH, pp ^= 1) {
    // write prefetched diff rows to transposed LDS
    if (t < 512) {
      sdT[gpart * 4 + 0][gr] = pf.x;
      sdT[gpart * 4 + 1][gr] = pf.y;
      sdT[gpart * 4 + 2][gr] = pf.z;
      sdT[gpart * 4 + 3][gr] = pf.w;
      if (gpart == 0) { sdT[32][gr] = pvalid ? 1.f : 0.f; sdT[33][gr] = 0.f; }
    }
    __syncthreads();
    // issue next chunk's gather (latency hides under expand + MFMA)
    if (t < 512) {
      int idx = cb + CH + gr;
      pvalid = (idx < nb);
      pf = make_float4(0.f, 0.f, 0.f, 0.f);
      if (pvalid) {
        float4 e = e4[rl[idx] * 8 + gpart];
        pf = make_float4(e.x - scen[gpart * 4], e.y - scen[gpart * 4 + 1],
                         e.z - scen[gpart * 4 + 2], e.w - scen[gpart * 4 + 3]);
      }
    }
    // expand: 2 bf16x8 units per thread; vector b128 LDS reads from sdT
    #pragma unroll
    for (int uu = 0; uu < 2; ++uu) {
      int unit = t + uu * 1024;
      int side = unit >> 10;
      int rem  = unit & 1023;
      int ch = rem >> 7, col = rem & 127;
      int gcol = (side ? Qt : Pt) * TILE + col;
      int u = tI0[gcol], v = tI1[gcol];
      const float4* pu = reinterpret_cast<const float4*>(&sdT[u][ch * 8]);
      const float4* pv = reinterpret_cast<const float4*>(&sdT[v][ch * 8]);
      float4 u0 = pu[0], u1 = pu[1], v0 = pv[0], v1 = pv[1];
      bf16x8 pk;
      pk[0] = (short)f2bf(u0.x * v0.x); pk[1] = (short)f2bf(u0.y * v0.y);
      pk[2] = (short)f2bf(u0.z * v0.z); pk[3] = (short)f2bf(u0.w * v0.w);
      pk[4] = (short)f2bf(u1.x * v1.x); pk[5] = (short)f2bf(u1.y * v1.y);
      pk[6] = (short)f2bf(u1.z * v1.z); pk[7] = (short)f2bf(u1.w * v1.w);
      *reinterpret_cast<bf16x8*>(&tiles[pp][side][ch][col][0]) = pk;
    }
    __syncthreads();
    // 2 K-steps x 4 MFMA per wave (fragment addressing family validated r8-r14)
    #pragma unroll
    for (int s = 0; s < 2; ++s) {
      bf16x8 a[2], b[2];
      #pragma unroll
      for (int f = 0; f < 2; ++f) {
        a[f] = *reinterpret_cast<const bf16x8*>(&tiles[pp][0][s * 4 + kg][wr * 32 + f * 16 + lr][0]);
        b[f] = *reinterpret_cast<const bf16x8*>(&tiles[pp][1][s * 4 + kg][wc * 32 + f * 16 + lr][0]);
      }
      #pragma unroll
      for (int fa = 0; fa < 2; ++fa)
        #pragma unroll
        for (int fc = 0; fc < 2; ++fc)
          acc[fa][fc] = __builtin_amdgcn_mfma_f32_16x16x32_bf16(a[fa], b[fc], acc[fa][fc], 0, 0, 0);
    }
  }
  __syncthreads();

  // ---- fused epilogue (same algebra; validated absmax=0 r2/r5/r6/r8/r10-r14) ----
  // C/D layout (m89-verified): Q(col) = lane&15, P(row) = (lane>>4)*4 + reg
  const int pb = Pt * TILE + wr * 32;
  const int qb = Qt * TILE + wc * 32;
  const float inv_cnt = 1.f / ((float)nb + 1e-7f);
  float sum = 0.f;
  #pragma unroll
  for (int fa = 0; fa < 2; ++fa) {
    #pragma unroll
    for (int r = 0; r < 4; ++r) {
      const int P = pb + fa * 16 + kg * 4 + r;
      const int i = tI0[P], j = tI1[P];
      #pragma unroll
      for (int fc = 0; fc < 2; ++fc) {
        const int Q = qb + fc * 16 + lr;
        const int li = tI0[Q], mi = tI1[Q];
        const float g = acc[fa][fc][r];
        if (P < NP) {
          if (Q < NP) {
            int s0 = min(i, li), x1 = max(i, li), x2 = min(j, mi), s3 = max(j, mi);
            int s1 = min(x1, x2), s2 = max(x1, x2);
            bool e01 = (s0 == s1), e12 = (s1 == s2), e23 = (s2 == s3);
            float wgt, tgt = 0.f;
            if (e01 && e12 && e23)                 wgt = 0.f;
            else if (e01 && e23)                   { wgt = 2.f / 9.f; tgt = T4C1; }
            else if ((e01 && e12) || (e12 && e23)) wgt = 0.25f;
            else if (e01 || e12 || e23)            wgt = 5.f / 24.f;
            else                                   wgt = 1.f / 6.f;
            float d = c4f(g) - tgt;
            sum += 0.125f * wgt * d * d;
          } else if (Q < 560) {
            if (Q - NP >= j) { float d = c3f(g); sum += 0.25f * d * d; }
          } else if (Q == 560) {
            if (i < j) { float d = c2f(g * inv_cnt); sum += 0.5f * d * d; }
          }
        } else if (P < 560 && Q == 560) {
          float m1 = g * inv_cnt;
          sum += m1 * m1;
        }
      }
    }
  }

  #pragma unroll
  for (int off = 32; off > 0; off >>= 1) sum += __shfl_down(sum, off, 64);
  if (lane == 0) sred[wid] = sum;
  __syncthreads();
  if (t == 0) {
    float s = 0.f;
    #pragma unroll
    for (int q = 0; q < 16; ++q) s += sred[q];
    atomicAdd(out, s * ((float)nb * (1.f / (float)B_N)));   // direct device-scope accumulate
  }
}

extern "C" void kernel_launch(void* const* d_in, const int* in_sizes, int n_in,
                              void* d_out, int out_size, void* d_ws, size_t ws_size,
                              hipStream_t stream) {
  const float* emb = (const float*)d_in[0];
  const float* cen = (const float*)d_in[1];
  const float* lg  = (const float*)d_in[2];
  float* out = (float*)d_out;

  (void)hipMemsetAsync(d_out, 0, (size_t)out_size * 4, stream);  // zero the accumulator
  k_main<<<dim3(NT, NT, K_N), 1024, 0, stream>>>(emb, cen, lg, out);
}